// Round 6
// baseline (362.400 us; speedup 1.0000x reference)
//
#include <hip/hip_runtime.h>
#include <hip/hip_bf16.h>

// GraphAttentionLayer: out = elu( softmax_row( where(adj>0, lrelu(src_i+dst_j), 0) ) @ wh )
//
// ===================== R6: DIAGNOSTIC ROUND =====================
// k2 has never been visible in rocprof top-5 (1GiB ws-poison fills ~150us mask
// it). Three structural theories (barrier drain R3, vmcnt order R4/R5, spill)
// all failed to move total time. This round:
//   - k2 REPEAT=4: accumulate 4 identical passes, scale 0.25 (DCE-proof,
//     deterministic) -> k2 tops the profile, exposing FETCH_SIZE / hbm_gbps /
//     VGPR / Occupancy / VALUBusy for a definitive bottleneck split.
//   - spill-safe: single B buffer, launch_bounds(256,2) (no reg cap pressure).
//   - drain-free: per iter, program order [load B(i) -> issue adj(i+1) ->
//     compute+MFMA], pinned with sched_barrier(0). MFMA waits vmcnt(4):
//     adj(i+1) stays in flight (vmcnt retires oldest-first).
//   - nt removed from loads so FETCH_SIZE is interpretable.
// NEXT ROUND: set REPEAT=1.

constexpr int N_ROWS = 8192;
constexpr int F_IN   = 128;
constexpr int F_OUT  = 64;
constexpr int REPEAT = 4;          // DIAGNOSTIC amplification of k2
#define LRELU_A 0.2f
#define LOG2E   1.4426950408889634f

// workspace layout (bytes)
constexpr size_t OFF_WHT  = 0;                    // 64*8192*2 = 1 MiB bf16 [f][row]
constexpr size_t OFF_SRC  = 1048576;              // 8192 f32 (pre-scaled by log2e)
constexpr size_t OFF_DST  = OFF_SRC + 32768;      // 8192 f32 (pre-scaled by log2e)
constexpr size_t OFF_LP   = OFF_DST + 32768;      // S*8192 f32 (S<=8)
constexpr size_t OFF_ACC  = OFF_LP + 8 * 32768;   // S*8192*64 f32

typedef __attribute__((ext_vector_type(4))) float f32x4;
typedef __attribute__((ext_vector_type(4))) int   i32x4;
typedef __attribute__((ext_vector_type(8))) short s16x8;

static __device__ __forceinline__ short f2bf(float f) {
  unsigned u = __float_as_uint(f);
  u = (u + 0x7fffu + ((u >> 16) & 1u)) >> 16;  // RNE
  return (short)u;
}

// ---------------- Kernel 1: wh = x@w ; src/dst (x log2e) ; whT (bf16) -------
__global__ __launch_bounds__(256) void k1_proj(
    const float* __restrict__ x, const float* __restrict__ w,
    const float* __restrict__ a, short* __restrict__ whT,
    float* __restrict__ src, float* __restrict__ dst)
{
  const int lane = threadIdx.x & 63;   // = output feature f
  const int wid  = threadIdx.x >> 6;
  const int rowBase = blockIdx.x * 32 + wid * 8;   // 8 rows per wave

  float acc[8];
#pragma unroll
  for (int r = 0; r < 8; ++r) acc[r] = 0.0f;

#pragma unroll 1
  for (int kc = 0; kc < 4; ++kc) {     // K chunks of 32 — ONE wreg live
    float wreg[32];
#pragma unroll
    for (int kk = 0; kk < 32; ++kk)
      wreg[kk] = w[(kc * 32 + kk) * F_OUT + lane];   // coalesced
#pragma unroll
    for (int r = 0; r < 8; ++r) {
      const f32x4* xp = (const f32x4*)(x + (size_t)(rowBase + r) * F_IN + kc * 32);
#pragma unroll
      for (int q = 0; q < 8; ++q) {    // wave-uniform broadcast loads
        f32x4 xv = xp[q];
        acc[r] = fmaf(xv.x, wreg[4*q+0], acc[r]);
        acc[r] = fmaf(xv.y, wreg[4*q+1], acc[r]);
        acc[r] = fmaf(xv.z, wreg[4*q+2], acc[r]);
        acc[r] = fmaf(xv.w, wreg[4*q+3], acc[r]);
      }
    }
  }

  s16x8 hb;
#pragma unroll
  for (int r = 0; r < 8; ++r) hb[r] = f2bf(acc[r]);
  *(s16x8*)&whT[(size_t)lane * N_ROWS + rowBase] = hb;

  const float aS = a[lane];
  const float aD = a[F_OUT + lane];
#pragma unroll
  for (int r = 0; r < 8; ++r) {
    float ts = acc[r] * aS;
    float td = acc[r] * aD;
#pragma unroll
    for (int off = 32; off > 0; off >>= 1) {
      ts += __shfl_xor(ts, off, 64);
      td += __shfl_xor(td, off, 64);
    }
    if (lane == 0) {
      src[rowBase + r] = ts * LOG2E;   // log2-domain scores
      dst[rowBase + r] = td * LOG2E;
    }
  }
}

// ---------------- Kernel 2: pipelined fused mask+exp+PV (diagnostic x4) -----
// grid: (N/64, S) x 256 threads (4 waves). Wave owns 16 rows x all 64 feats.
// A-fragment per-lane in registers (row=lane&15, k=(lane>>4)*8+j).
template<int S>
__global__ __launch_bounds__(256, 2) void k2_attn(
    const int* __restrict__ adj, const short* __restrict__ whT,
    const float* __restrict__ src, const float* __restrict__ dst,
    float* __restrict__ acc_part, float* __restrict__ l_part)
{
  constexpr int JLEN = N_ROWS / S;
  constexpr int NI   = JLEN / 64;   // 64-col iterations (even)
  __shared__ float Dlds[JLEN];

  const int lane = threadIdx.x & 63;
  const int wid  = threadIdx.x >> 6;
  const int s    = blockIdx.y;
  const int jbase = s * JLEN;
  const int rowg = blockIdx.x * 64 + wid * 16;
  const int r16  = lane & 15;
  const int kq   = lane >> 4;

  // stage dst slice once (lgkm stream; one barrier before the pipeline)
  for (int t = threadIdx.x * 4; t < JLEN; t += 1024)
    *(f32x4*)&Dlds[t] = *(const f32x4*)(dst + jbase + t);
  __syncthreads();

  const size_t arow = (size_t)(rowg + r16) * N_ROWS;
  const float sv = src[rowg + r16];               // already * log2e
  const int cb0 = jbase + kq * 8;
  const short* bbase = whT + (size_t)r16 * N_ROWS;

  f32x4 acc0 = {0,0,0,0}, acc1 = {0,0,0,0}, acc2 = {0,0,0,0}, acc3 = {0,0,0,0};
  float lp = 0.0f;

  i32x4 Aa[4], Ab[4];       // adj double-buffer only (B loads are L2 hits)

  auto issueAdj = [&](i32x4* A, int i) {
    const int* p = adj + arow + cb0 + i * 64;
    A[0] = *(const i32x4*)(p);
    A[1] = *(const i32x4*)(p + 4);
    A[2] = *(const i32x4*)(p + 32);
    A[3] = *(const i32x4*)(p + 36);
  };

  auto body = [&](i32x4* CUR, i32x4* NXT, int i) {
    const int c = cb0 + i * 64;
    // --- [1] B(i) fragment loads (L2-resident whT) — OLDEST vmem this iter ---
    s16x8 Bc[8];
    {
      const short* bq = bbase + c;
#pragma unroll
      for (int f = 0; f < 4; ++f) {
        Bc[f]     = *(const s16x8*)(bq + (size_t)f * 16 * N_ROWS);
        Bc[4 + f] = *(const s16x8*)(bq + (size_t)f * 16 * N_ROWS + 32);
      }
    }
    __builtin_amdgcn_sched_barrier(0);   // pin: B before adj in issue order
    // --- [2] adj(i+1) prefetch — NEWEST vmem; never drained below ---
    if (i + 1 < NI) issueAdj(NXT, i + 1);
    __builtin_amdgcn_sched_barrier(0);   // pin: adj before compute/MFMA
    // --- [3] compute P(i) from CUR (waits vmcnt(12): leaves B+adj in flight)
    const int db = kq * 8 + (i & (NI - 1)) * 64;
#pragma unroll
    for (int h = 0; h < 2; ++h) {
      const f32x4 dA = *(const f32x4*)&Dlds[db + h * 32];
      const f32x4 dB = *(const f32x4*)&Dlds[db + h * 32 + 4];
      const i32x4 aA = CUR[2 * h];
      const i32x4 aB = CUR[2 * h + 1];
      float p0, p1, p2, p3, p4, p5, p6, p7;
#define PE(pp, dd, aa) { float e = sv + (dd); e = fmaxf(e, LRELU_A * e); \
                         (pp) = ((aa) > 0) ? __builtin_amdgcn_exp2f(e) : 1.0f; }
      PE(p0, dA.x, aA.x) PE(p1, dA.y, aA.y) PE(p2, dA.z, aA.z) PE(p3, dA.w, aA.w)
      PE(p4, dB.x, aB.x) PE(p5, dB.y, aB.y) PE(p6, dB.z, aB.z) PE(p7, dB.w, aB.w)
#undef PE
      lp += ((p0 + p1) + (p2 + p3)) + ((p4 + p5) + (p6 + p7));
      union { s16x8 v; __hip_bfloat16 b[8]; } u;
      u.b[0] = __float2bfloat16(p0); u.b[1] = __float2bfloat16(p1);
      u.b[2] = __float2bfloat16(p2); u.b[3] = __float2bfloat16(p3);
      u.b[4] = __float2bfloat16(p4); u.b[5] = __float2bfloat16(p5);
      u.b[6] = __float2bfloat16(p6); u.b[7] = __float2bfloat16(p7);
      // --- [4] MFMA: waits vmcnt(4) for B(i); adj(i+1) stays in flight ---
      acc0 = __builtin_amdgcn_mfma_f32_16x16x32_bf16(u.v, Bc[h * 4 + 0], acc0, 0, 0, 0);
      acc1 = __builtin_amdgcn_mfma_f32_16x16x32_bf16(u.v, Bc[h * 4 + 1], acc1, 0, 0, 0);
      acc2 = __builtin_amdgcn_mfma_f32_16x16x32_bf16(u.v, Bc[h * 4 + 2], acc2, 0, 0, 0);
      acc3 = __builtin_amdgcn_mfma_f32_16x16x32_bf16(u.v, Bc[h * 4 + 3], acc3, 0, 0, 0);
    }
  };

#pragma unroll 1
  for (int rep = 0; rep < REPEAT; ++rep) {   // DIAGNOSTIC: 4 identical passes,
    issueAdj(Aa, 0);                          // results accumulated, scaled 1/4
#pragma unroll 1
    for (int i = 0; i < NI; i += 2) {
      body(Aa, Ab, i);
      body(Ab, Aa, i + 1);
    }
  }

  // ---- epilogue (scale by 1/REPEAT) ----
  lp *= (1.0f / REPEAT);
  lp += __shfl_xor(lp, 16, 64);
  lp += __shfl_xor(lp, 32, 64);
  if (lane < 16) l_part[(size_t)s * N_ROWS + rowg + lane] = lp;

  const float sc = 1.0f / REPEAT;
#define STORE_ACC(av, nt) _Pragma("unroll") \
  for (int rg = 0; rg < 4; ++rg) { \
    const int row = rowg + kq * 4 + rg; \
    __builtin_nontemporal_store((av)[rg] * sc, \
        acc_part + ((size_t)s * N_ROWS + row) * F_OUT + (nt) * 16 + r16); \
  }
  STORE_ACC(acc0, 0) STORE_ACC(acc1, 1) STORE_ACC(acc2, 2) STORE_ACC(acc3, 3)
#undef STORE_ACC
}

// ---------------- Kernel 3: combine partials, normalize, ELU ----------------
template<int S>
__global__ __launch_bounds__(256) void k3_combine(
    const float* __restrict__ acc_part, const float* __restrict__ l_part,
    float* __restrict__ out)
{
  const int idx = blockIdx.x * 256 + threadIdx.x;  // over N*F/4
  const int row = idx >> 4;          // F_OUT/4 = 16
  const int f4  = idx & 15;
  f32x4 h = {0.f, 0.f, 0.f, 0.f};
  float l = 0.f;
#pragma unroll
  for (int s = 0; s < S; ++s) {
    h += *(const f32x4*)(acc_part + ((size_t)s * N_ROWS + row) * F_OUT + 4 * f4);
    l += l_part[(size_t)s * N_ROWS + row];
  }
  const float inv = 1.0f / l;
  f32x4 o;
  {
    float v0 = h.x * inv; o.x = v0 > 0.f ? v0 : (__expf(v0) - 1.0f);
    float v1 = h.y * inv; o.y = v1 > 0.f ? v1 : (__expf(v1) - 1.0f);
    float v2 = h.z * inv; o.z = v2 > 0.f ? v2 : (__expf(v2) - 1.0f);
    float v3 = h.w * inv; o.w = v3 > 0.f ? v3 : (__expf(v3) - 1.0f);
  }
  *(f32x4*)(out + (size_t)row * F_OUT + 4 * f4) = o;
}

// ---------------- launch ----------------
extern "C" void kernel_launch(void* const* d_in, const int* in_sizes, int n_in,
                              void* d_out, int out_size, void* d_ws, size_t ws_size,
                              hipStream_t stream) {
  const float* x   = (const float*)d_in[0];
  const int*   adj = (const int*)d_in[1];
  const float* w   = (const float*)d_in[2];
  const float* a   = (const float*)d_in[3];
  float* out = (float*)d_out;
  char* ws = (char*)d_ws;

  short* whT      = (short*)(ws + OFF_WHT);
  float* src      = (float*)(ws + OFF_SRC);
  float* dst      = (float*)(ws + OFF_DST);
  float* l_part   = (float*)(ws + OFF_LP);
  float* acc_part = (float*)(ws + OFF_ACC);

  k1_proj<<<N_ROWS / 32, 256, 0, stream>>>(x, w, a, whT, src, dst);

  if (ws_size >= OFF_ACC + 8ull * N_ROWS * F_OUT * 4) {
    k2_attn<8><<<dim3(N_ROWS / 64, 8), 256, 0, stream>>>(adj, whT, src, dst,
                                                         acc_part, l_part);
    k3_combine<8><<<(N_ROWS * F_OUT / 4) / 256, 256, 0, stream>>>(acc_part, l_part, out);
  } else {
    k2_attn<2><<<dim3(N_ROWS / 64, 2), 256, 0, stream>>>(adj, whT, src, dst,
                                                         acc_part, l_part);
    k3_combine<2><<<(N_ROWS * F_OUT / 4) / 256, 256, 0, stream>>>(acc_part, l_part, out);
  }
}

// Round 7
// 109.918 us; speedup vs baseline: 3.2970x; 3.2970x over previous
//
#include <hip/hip_runtime.h>
#include <hip/hip_bf16.h>

// GraphAttentionLayer: out = elu( softmax_row( where(adj>0, lrelu(src_i+dst_j), 0) ) @ wh )
//
// R6 diagnosis (REPEAT=4 profile): k2 latency-bound with ALL pipes idle
// (VALU 17.6%, MFMA 3.6%, HBM 1.44 TB/s, no spill). Root cause: 8 KB/iter of
// whT B-fragment vmem per 4 KB adj; adj stream thrashes L2 -> B loads are L3
// hits at ~500cy, exposed every iteration in every prior variant.
// R7: whT slice (64 feats x 512 cols bf16 = 64KB) staged in LDS ONCE per
// block; K-loop vmem = adj ONLY (double-buffered, vmcnt(4)); B via swizzled
// ds_read_b128; dst in LDS. S=16 j-splits, 512-thread blocks (8 waves x 16
// rows), 2 blocks/CU (66KB LDS), 16 waves/CU.

constexpr int N_ROWS = 8192;
constexpr int F_IN   = 128;
constexpr int F_OUT  = 64;
#define LRELU_A 0.2f
#define LOG2E   1.4426950408889634f

// workspace layout (bytes)
constexpr size_t OFF_WHT  = 0;                    // 64*8192*2 = 1 MiB bf16 [f][row]
constexpr size_t OFF_SRC  = 1048576;              // 8192 f32 (pre-scaled by log2e)
constexpr size_t OFF_DST  = OFF_SRC + 32768;      // 8192 f32 (pre-scaled by log2e)
constexpr size_t OFF_LP   = OFF_DST + 32768;      // S*8192 f32 (S<=16)
constexpr size_t OFF_ACC  = OFF_LP + 16 * 32768;  // S*8192*64 f32

typedef __attribute__((ext_vector_type(4))) float f32x4;
typedef __attribute__((ext_vector_type(4))) int   i32x4;
typedef __attribute__((ext_vector_type(8))) short s16x8;

static __device__ __forceinline__ short f2bf(float f) {
  unsigned u = __float_as_uint(f);
  u = (u + 0x7fffu + ((u >> 16) & 1u)) >> 16;  // RNE
  return (short)u;
}

// ---------------- Kernel 1: wh = x@w ; src/dst (x log2e) ; whT (bf16) -------
__global__ __launch_bounds__(256) void k1_proj(
    const float* __restrict__ x, const float* __restrict__ w,
    const float* __restrict__ a, short* __restrict__ whT,
    float* __restrict__ src, float* __restrict__ dst)
{
  const int lane = threadIdx.x & 63;   // = output feature f
  const int wid  = threadIdx.x >> 6;
  const int rowBase = blockIdx.x * 32 + wid * 8;   // 8 rows per wave

  float acc[8];
#pragma unroll
  for (int r = 0; r < 8; ++r) acc[r] = 0.0f;

#pragma unroll 1
  for (int kc = 0; kc < 4; ++kc) {     // K chunks of 32 — ONE wreg live
    float wreg[32];
#pragma unroll
    for (int kk = 0; kk < 32; ++kk)
      wreg[kk] = w[(kc * 32 + kk) * F_OUT + lane];   // coalesced
#pragma unroll
    for (int r = 0; r < 8; ++r) {
      const f32x4* xp = (const f32x4*)(x + (size_t)(rowBase + r) * F_IN + kc * 32);
#pragma unroll
      for (int q = 0; q < 8; ++q) {    // wave-uniform broadcast loads
        f32x4 xv = xp[q];
        acc[r] = fmaf(xv.x, wreg[4*q+0], acc[r]);
        acc[r] = fmaf(xv.y, wreg[4*q+1], acc[r]);
        acc[r] = fmaf(xv.z, wreg[4*q+2], acc[r]);
        acc[r] = fmaf(xv.w, wreg[4*q+3], acc[r]);
      }
    }
  }

  s16x8 hb;
#pragma unroll
  for (int r = 0; r < 8; ++r) hb[r] = f2bf(acc[r]);
  *(s16x8*)&whT[(size_t)lane * N_ROWS + rowBase] = hb;

  const float aS = a[lane];
  const float aD = a[F_OUT + lane];
#pragma unroll
  for (int r = 0; r < 8; ++r) {
    float ts = acc[r] * aS;
    float td = acc[r] * aD;
#pragma unroll
    for (int off = 32; off > 0; off >>= 1) {
      ts += __shfl_xor(ts, off, 64);
      td += __shfl_xor(td, off, 64);
    }
    if (lane == 0) {
      src[rowBase + r] = ts * LOG2E;   // log2-domain scores
      dst[rowBase + r] = td * LOG2E;
    }
  }
}

// ---------------- Kernel 2: fused mask+exp+PV, LDS-resident B ----------------
// grid: (N/128, S) x 512 threads (8 waves, 16 rows each).
// K-loop vmem = adj only. B fragments from swizzled LDS (whT slice).
template<int S>
__global__ __launch_bounds__(512, 3) void k2_attn(
    const int* __restrict__ adj, const short* __restrict__ whT,
    const float* __restrict__ src, const float* __restrict__ dst,
    float* __restrict__ acc_part, float* __restrict__ l_part)
{
  constexpr int JLEN = N_ROWS / S;   // 512
  constexpr int NI   = JLEN / 64;    // 8 (even)
  __shared__ short Blds[64 * JLEN];  // 64 KB, swizzled: byte ^= (f&7)<<4
  __shared__ float Dlds[JLEN];       // 2 KB

  const int tid  = threadIdx.x;
  const int lane = tid & 63;
  const int wid  = tid >> 6;
  const int s    = blockIdx.y;
  const int jbase = s * JLEN;
  const int rowg = blockIdx.x * 128 + wid * 16;
  const int r16  = lane & 15;
  const int kq   = lane >> 4;

  // ---- stage whT slice (swizzled) + dst slice; ONE barrier ----
#pragma unroll
  for (int q = 0; q < (64 * JLEN / 8) / 512; ++q) {   // 16B chunks
    const int m   = tid + q * 512;
    const int f   = m >> 6;            // JLEN*2/16 = 64 chunks per feature row
    const int c16 = m & 63;
    const s16x8 v = *(const s16x8*)(whT + (size_t)f * N_ROWS + jbase + c16 * 8);
    *(s16x8*)((char*)Blds + f * (JLEN * 2) + ((c16 * 16) ^ ((f & 7) << 4))) = v;
  }
  if (tid < JLEN / 4)
    *(f32x4*)&Dlds[tid * 4] = *(const f32x4*)(dst + jbase + tid * 4);
  __syncthreads();

  const size_t arow = (size_t)(rowg + r16) * N_ROWS;
  const float sv = src[rowg + r16];               // already * log2e
  const int cb0 = jbase + kq * 8;

  f32x4 acc0 = {0,0,0,0}, acc1 = {0,0,0,0}, acc2 = {0,0,0,0}, acc3 = {0,0,0,0};
  float lp = 0.0f;

  i32x4 Aa[4], Ab[4];                  // adj double-buffer (only loop vmem)

  auto issueAdj = [&](i32x4* A, int i) {
    const int* p = adj + arow + cb0 + i * 64;
    A[0] = __builtin_nontemporal_load((const i32x4*)(p));
    A[1] = __builtin_nontemporal_load((const i32x4*)(p + 4));
    A[2] = __builtin_nontemporal_load((const i32x4*)(p + 32));
    A[3] = __builtin_nontemporal_load((const i32x4*)(p + 36));
  };

  auto body = [&](i32x4* CUR, i32x4* NXT, int i) {
    // --- [1] B(i) from LDS (lgkm stream; latency hidden under vmcnt wait) ---
    s16x8 Bc[8];
    {
      const int cswz = (r16 & 7) << 4;
#pragma unroll
      for (int h = 0; h < 2; ++h)
#pragma unroll
        for (int ft = 0; ft < 4; ++ft) {
          const int colb = (i * 64 + kq * 8 + h * 32) * 2;
          Bc[h * 4 + ft] = *(const s16x8*)((char*)Blds
              + (ft * 16 + r16) * (JLEN * 2) + (colb ^ cswz));
        }
    }
    // --- [2] adj(i+1) prefetch — newest vmem, stays in flight below ---
    if (i + 1 < NI) issueAdj(NXT, i + 1);
    __builtin_amdgcn_sched_barrier(0);
    // --- [3] compute P(i); wait = vmcnt(4) for adj(i), lgkm for B ---
#pragma unroll
    for (int h = 0; h < 2; ++h) {
      const int db = kq * 8 + i * 64 + h * 32;
      const f32x4 dA = *(const f32x4*)&Dlds[db];
      const f32x4 dB = *(const f32x4*)&Dlds[db + 4];
      const i32x4 aA = CUR[2 * h];
      const i32x4 aB = CUR[2 * h + 1];
      float p0, p1, p2, p3, p4, p5, p6, p7;
#define PE(pp, dd, aa) { float e = sv + (dd); e = fmaxf(e, LRELU_A * e); \
                         (pp) = ((aa) > 0) ? __builtin_amdgcn_exp2f(e) : 1.0f; }
      PE(p0, dA.x, aA.x) PE(p1, dA.y, aA.y) PE(p2, dA.z, aA.z) PE(p3, dA.w, aA.w)
      PE(p4, dB.x, aB.x) PE(p5, dB.y, aB.y) PE(p6, dB.z, aB.z) PE(p7, dB.w, aB.w)
#undef PE
      lp += ((p0 + p1) + (p2 + p3)) + ((p4 + p5) + (p6 + p7));
      union { s16x8 v; __hip_bfloat16 b[8]; } u;
      u.b[0] = __float2bfloat16(p0); u.b[1] = __float2bfloat16(p1);
      u.b[2] = __float2bfloat16(p2); u.b[3] = __float2bfloat16(p3);
      u.b[4] = __float2bfloat16(p4); u.b[5] = __float2bfloat16(p5);
      u.b[6] = __float2bfloat16(p6); u.b[7] = __float2bfloat16(p7);
      acc0 = __builtin_amdgcn_mfma_f32_16x16x32_bf16(u.v, Bc[h * 4 + 0], acc0, 0, 0, 0);
      acc1 = __builtin_amdgcn_mfma_f32_16x16x32_bf16(u.v, Bc[h * 4 + 1], acc1, 0, 0, 0);
      acc2 = __builtin_amdgcn_mfma_f32_16x16x32_bf16(u.v, Bc[h * 4 + 2], acc2, 0, 0, 0);
      acc3 = __builtin_amdgcn_mfma_f32_16x16x32_bf16(u.v, Bc[h * 4 + 3], acc3, 0, 0, 0);
    }
  };

  issueAdj(Aa, 0);                    // prologue
#pragma unroll 1
  for (int i = 0; i < NI; i += 2) {   // static buffer names
    body(Aa, Ab, i);
    body(Ab, Aa, i + 1);
  }

  // ---- epilogue ----
  lp += __shfl_xor(lp, 16, 64);       // lanes {l, l^16, l^32, l^48}: same row
  lp += __shfl_xor(lp, 32, 64);
  if (lane < 16) l_part[(size_t)s * N_ROWS + rowg + lane] = lp;

  // C/D layout: col(feature offset) = lane&15, row = (lane>>4)*4 + reg
#define STORE_ACC(av, nt) _Pragma("unroll") \
  for (int rg = 0; rg < 4; ++rg) { \
    const int row = rowg + kq * 4 + rg; \
    __builtin_nontemporal_store((av)[rg], \
        acc_part + ((size_t)s * N_ROWS + row) * F_OUT + (nt) * 16 + r16); \
  }
  STORE_ACC(acc0, 0) STORE_ACC(acc1, 1) STORE_ACC(acc2, 2) STORE_ACC(acc3, 3)
#undef STORE_ACC
}

// ---------------- Kernel 3: combine partials, normalize, ELU ----------------
template<int S>
__global__ __launch_bounds__(256) void k3_combine(
    const float* __restrict__ acc_part, const float* __restrict__ l_part,
    float* __restrict__ out)
{
  const int idx = blockIdx.x * 256 + threadIdx.x;  // over N*F/4
  const int row = idx >> 4;          // F_OUT/4 = 16
  const int f4  = idx & 15;
  f32x4 h = {0.f, 0.f, 0.f, 0.f};
  float l = 0.f;
#pragma unroll
  for (int s = 0; s < S; ++s) {
    h += *(const f32x4*)(acc_part + ((size_t)s * N_ROWS + row) * F_OUT + 4 * f4);
    l += l_part[(size_t)s * N_ROWS + row];
  }
  const float inv = 1.0f / l;
  f32x4 o;
  {
    float v0 = h.x * inv; o.x = v0 > 0.f ? v0 : (__expf(v0) - 1.0f);
    float v1 = h.y * inv; o.y = v1 > 0.f ? v1 : (__expf(v1) - 1.0f);
    float v2 = h.z * inv; o.z = v2 > 0.f ? v2 : (__expf(v2) - 1.0f);
    float v3 = h.w * inv; o.w = v3 > 0.f ? v3 : (__expf(v3) - 1.0f);
  }
  *(f32x4*)(out + (size_t)row * F_OUT + 4 * f4) = o;
}

// ---------------- launch ----------------
extern "C" void kernel_launch(void* const* d_in, const int* in_sizes, int n_in,
                              void* d_out, int out_size, void* d_ws, size_t ws_size,
                              hipStream_t stream) {
  const float* x   = (const float*)d_in[0];
  const int*   adj = (const int*)d_in[1];
  const float* w   = (const float*)d_in[2];
  const float* a   = (const float*)d_in[3];
  float* out = (float*)d_out;
  char* ws = (char*)d_ws;

  short* whT      = (short*)(ws + OFF_WHT);
  float* src      = (float*)(ws + OFF_SRC);
  float* dst      = (float*)(ws + OFF_DST);
  float* l_part   = (float*)(ws + OFF_LP);
  float* acc_part = (float*)(ws + OFF_ACC);

  k1_proj<<<N_ROWS / 32, 256, 0, stream>>>(x, w, a, whT, src, dst);

  // S=16: needs OFF_ACC + 32 MiB of workspace (~34.5 MiB total; ws is ~1 GiB)
  k2_attn<16><<<dim3(N_ROWS / 128, 16), 512, 0, stream>>>(adj, whT, src, dst,
                                                          acc_part, l_part);
  k3_combine<16><<<(N_ROWS * F_OUT / 4) / 256, 256, 0, stream>>>(acc_part, l_part, out);
}